// Round 3
// baseline (625.842 us; speedup 1.0000x reference)
//
#include <hip/hip_runtime.h>
#include <cstdint>

#define N_NODES 100000
#define N_EDGES 1600000
#define SCAN_NB 391   // ceil(N_NODES/256)
#define YD 12         // padded projected dim: [hw0..7, p1, p2, pad, pad]
#define SC_RANGE 12500

// ---------------- prep: M = [W1 | u1 | u2 | 0 0], w0m = W0 @ M, kc ----------------
__global__ __launch_bounds__(256) void k_prep(
    const float* __restrict__ W0, const float* __restrict__ b0,
    const float* __restrict__ W1,
    const float* __restrict__ Wnb, const float* __restrict__ bnb,
    const float* __restrict__ Wself, const float* __restrict__ bself,
    const float* __restrict__ Watt, const float* __restrict__ batt,
    float* __restrict__ w0m, float* __restrict__ kc) {
  __shared__ float M[32][YD];
  int t = threadIdx.x;
  if (t < 32) {
    for (int j = 0; j < 8; ++j) M[t][j] = W1[t * 8 + j];
    float a1 = 0.f, a2 = 0.f;
    for (int j = 0; j < 8; ++j) {
      a1 += Wnb[t * 8 + j] * Watt[j];
      a2 += Wself[t * 8 + j] * Watt[8 + j];
    }
    M[t][8] = a1; M[t][9] = a2; M[t][10] = 0.f; M[t][11] = 0.f;
  }
  __syncthreads();
  for (int o = t; o < 512 * YD; o += 256) {
    int k = o / YD, j = o % YD;
    float a = 0.f;
    for (int m = 0; m < 32; ++m) a += W0[k * 32 + m] * M[m][j];
    w0m[o] = a;
  }
  if (t < YD) {
    float a = 0.f;
    for (int m = 0; m < 32; ++m) a += b0[m] * M[m][t];
    if (t == 8) { for (int j = 0; j < 8; ++j) a += bnb[j] * Watt[j]; a += batt[0]; }
    if (t == 9) { for (int j = 0; j < 8; ++j) a += bself[j] * Watt[8 + j]; }
    kc[t] = a;
  }
}

// ---------------- y = x @ w0m  [100000,512]x[512,10->12], wave per row ----------------
__global__ __launch_bounds__(256) void k_gemm_y(const float* __restrict__ x,
                                                const float* __restrict__ w0m,
                                                float* __restrict__ y) {
  int lane = threadIdx.x & 63;
  int wave = (blockIdx.x * 256 + threadIdx.x) >> 6;  // 0..24999
  float wreg[8][10];
  const float* wp = w0m + lane * 8 * YD;
#pragma unroll
  for (int m = 0; m < 8; ++m)
#pragma unroll
    for (int j = 0; j < 10; ++j) wreg[m][j] = wp[m * YD + j];
  for (int row = wave; row < N_NODES; row += 25000) {
    const float* xr = x + (size_t)row * 512 + lane * 8;
    float4 a0 = *(const float4*)xr;
    float4 a1 = *(const float4*)(xr + 4);
    float xv[8] = {a0.x, a0.y, a0.z, a0.w, a1.x, a1.y, a1.z, a1.w};
    float acc[10];
#pragma unroll
    for (int j = 0; j < 10; ++j) acc[j] = 0.f;
#pragma unroll
    for (int m = 0; m < 8; ++m)
#pragma unroll
      for (int j = 0; j < 10; ++j) acc[j] += xv[m] * wreg[m][j];
#pragma unroll
    for (int d = 1; d < 64; d <<= 1)
#pragma unroll
      for (int j = 0; j < 10; ++j) acc[j] += __shfl_xor(acc[j], d, 64);
    if (lane == 0) {
      float* yp = y + (size_t)row * YD;
      *(float4*)yp       = make_float4(acc[0], acc[1], acc[2], acc[3]);
      *(float4*)(yp + 4) = make_float4(acc[4], acc[5], acc[6], acc[7]);
      *(float4*)(yp + 8) = make_float4(acc[8], acc[9], 0.f, 0.f);
    }
  }
}

// ---------------- CSR build ----------------
__global__ void k_zero_cnt(int* __restrict__ cnt, int n) {
  int i = blockIdx.x * 256 + threadIdx.x;
  if (i < n) cnt[i] = 0;
}

__global__ void k_count4(const int* __restrict__ col, int* __restrict__ cnt) {
  int e0 = (blockIdx.x * 256 + threadIdx.x) * 4;
  if (e0 >= N_EDGES) return;
  int4 c = *(const int4*)(col + e0);
  atomicAdd(&cnt[c.x], 1); atomicAdd(&cnt[c.y], 1);
  atomicAdd(&cnt[c.z], 1); atomicAdd(&cnt[c.w], 1);
}

__global__ __launch_bounds__(256) void k_scan1(const int* __restrict__ cnt,
                                               int* __restrict__ off,
                                               int* __restrict__ bsum) {
  __shared__ int s[256];
  int t = threadIdx.x;
  int i = blockIdx.x * 256 + t;
  int v = (i < N_NODES) ? cnt[i] : 0;
  s[t] = v;
  __syncthreads();
  for (int d = 1; d < 256; d <<= 1) {
    int a = (t >= d) ? s[t - d] : 0;
    __syncthreads();
    s[t] += a;
    __syncthreads();
  }
  if (i < N_NODES) off[i] = s[t] - v;
  if (t == 255) bsum[blockIdx.x] = s[255];
}

__global__ __launch_bounds__(512) void k_scan2(const int* __restrict__ bsum,
                                               int* __restrict__ bpre) {
  __shared__ int s[512];
  int t = threadIdx.x;
  int v = (t < SCAN_NB) ? bsum[t] : 0;
  s[t] = v;
  __syncthreads();
  for (int d = 1; d < 512; d <<= 1) {
    int a = (t >= d) ? s[t - d] : 0;
    __syncthreads();
    s[t] += a;
    __syncthreads();
  }
  if (t < SCAN_NB) bpre[t] = s[t] - v;
}

__global__ void k_scan3(const int* __restrict__ cnt, const int* __restrict__ bpre,
                        int* __restrict__ off, int* __restrict__ cursor,
                        float* __restrict__ dinv1) {
  int i = blockIdx.x * 256 + threadIdx.x;
  if (i >= N_NODES) return;
  int o = off[i] + bpre[i >> 8];
  off[i] = o;
  cursor[i] = o;
  dinv1[i] = rsqrtf((float)cnt[i] + 1.0f);
  if (i == 0) off[N_NODES] = N_EDGES;
}

// XCD-localized scatter: range = blockIdx & 7 -> (heuristically) one XCD owns
// one 12500-node destination range, so its ssrc writes stay in its own L2.
__global__ void k_scatter(const int* __restrict__ row, const int* __restrict__ col,
                          int* __restrict__ cursor, int* __restrict__ ssrc) {
  int range = blockIdx.x & 7;
  int chunk = blockIdx.x >> 3;
  int e0 = (chunk * 256 + threadIdx.x) * 4;
  if (e0 >= N_EDGES) return;
  int lo = range * SC_RANGE, hi = lo + SC_RANGE;
  int4 c4 = *(const int4*)(col + e0);
  int4 r4 = *(const int4*)(row + e0);
  int cs[4] = {c4.x, c4.y, c4.z, c4.w};
  int rs[4] = {r4.x, r4.y, r4.z, r4.w};
#pragma unroll
  for (int k = 0; k < 4; ++k) {
    int c = cs[k];
    if (c >= lo && c < hi) {
      int p = atomicAdd(&cursor[c], 1);
      ssrc[p] = rs[k];
    }
  }
}

// ---------------- conv1 aggregation on projected 10-dim y ----------------
// hw[i][0:8] = di*sum(dr*y[r][0:8]) + di^2*y[i][0:8] + kc[0:8]
// s1c[i]     = di*sum(dr*y[r][8])   + di^2*y[i][8]   + kc[8]   (s2c analogous)
__global__ void k_agg1(const int* __restrict__ off, const int* __restrict__ ssrc,
                       const float* __restrict__ y, const float* __restrict__ dinv1,
                       const float* __restrict__ kc, float* __restrict__ hw,
                       float* __restrict__ s1c, float* __restrict__ s2c) {
  int tid = blockIdx.x * 256 + threadIdx.x;  // N*4
  if (tid >= N_NODES * 4) return;
  int i = tid >> 2, q = tid & 3;
  if (q == 3) return;
  int p0 = off[i], p1 = off[i + 1];
  float di = dinv1[i];
  float d2 = di * di;
  if (q < 2) {
    float4 acc = make_float4(0.f, 0.f, 0.f, 0.f);
    for (int p = p0; p < p1; ++p) {
      int r = ssrc[p];
      float dr = dinv1[r];
      float4 v = *(const float4*)(y + (size_t)r * YD + q * 4);
      acc.x += v.x * dr; acc.y += v.y * dr; acc.z += v.z * dr; acc.w += v.w * dr;
    }
    float4 sv = *(const float4*)(y + (size_t)i * YD + q * 4);
    float4 kq = *(const float4*)(kc + q * 4);
    *(float4*)(hw + (size_t)i * 8 + q * 4) =
        make_float4(di * acc.x + d2 * sv.x + kq.x, di * acc.y + d2 * sv.y + kq.y,
                    di * acc.z + d2 * sv.z + kq.z, di * acc.w + d2 * sv.w + kq.w);
  } else {
    float a8 = 0.f, a9 = 0.f;
    for (int p = p0; p < p1; ++p) {
      int r = ssrc[p];
      float dr = dinv1[r];
      float4 v = *(const float4*)(y + (size_t)r * YD + 8);
      a8 += v.x * dr; a9 += v.y * dr;
    }
    float4 sv = *(const float4*)(y + (size_t)i * YD + 8);
    s1c[i] = di * a8 + d2 * sv.x + kc[8];
    s2c[i] = di * a9 + d2 * sv.y + kc[9];
  }
}

// ---------------- deg2 gather (gate on the fly) ----------------
__global__ void k_deg2g(const int* __restrict__ off, const int* __restrict__ ssrc,
                        const float* __restrict__ s1c, const float* __restrict__ s2c,
                        float* __restrict__ dinv2) {
  int i = blockIdx.x * 256 + threadIdx.x;
  if (i >= N_NODES) return;
  float s2i = s2c[i];
  float sum = 0.f;
  int p1 = off[i + 1];
  for (int p = off[i]; p < p1; ++p) {
    int r = ssrc[p];
    float w = fmaxf(s1c[r] + s2i, 0.f);
    float m = fminf(1.01f / (1.f + __expf(-w)), 1.f);
    sum += m * w;
  }
  dinv2[i] = rsqrtf(sum + 1.0f);
}

// ---------------- conv2 gather, self-loop + bias fused ----------------
__global__ void k_conv2g(const int* __restrict__ off, const int* __restrict__ ssrc,
                         const float* __restrict__ hw, const float* __restrict__ s1c,
                         const float* __restrict__ s2c, const float* __restrict__ dinv2,
                         const float* __restrict__ b1, float* __restrict__ out) {
  int tid = blockIdx.x * 256 + threadIdx.x;  // N*2
  if (tid >= N_NODES * 2) return;
  int i = tid >> 1, q = tid & 1;
  float s2i = s2c[i];
  float di = dinv2[i];
  float4 acc = make_float4(0.f, 0.f, 0.f, 0.f);
  int p1 = off[i + 1];
  for (int p = off[i]; p < p1; ++p) {
    int r = ssrc[p];
    float w = fmaxf(s1c[r] + s2i, 0.f);
    float m = fminf(1.01f / (1.f + __expf(-w)), 1.f);
    float cf = m * w * dinv2[r];
    float4 v = *(const float4*)(hw + (size_t)r * 8 + q * 4);
    acc.x += v.x * cf; acc.y += v.y * cf; acc.z += v.z * cf; acc.w += v.w * cf;
  }
  float4 sv = *(const float4*)(hw + (size_t)i * 8 + q * 4);
  float4 bq = *(const float4*)(b1 + q * 4);
  float d2 = di * di;
  *(float4*)(out + (size_t)i * 8 + q * 4) =
      make_float4(di * acc.x + d2 * sv.x + bq.x, di * acc.y + d2 * sv.y + bq.y,
                  di * acc.z + d2 * sv.z + bq.z, di * acc.w + d2 * sv.w + bq.w);
}

extern "C" void kernel_launch(void* const* d_in, const int* in_sizes, int n_in,
                              void* d_out, int out_size, void* d_ws, size_t ws_size,
                              hipStream_t stream) {
  const float* x     = (const float*)d_in[0];
  const int*   eidx  = (const int*)d_in[1];
  const int*   row   = eidx;
  const int*   col   = eidx + N_EDGES;
  const float* W0    = (const float*)d_in[2];
  const float* b0    = (const float*)d_in[3];
  const float* W1    = (const float*)d_in[4];
  const float* b1    = (const float*)d_in[5];
  const float* Wnb   = (const float*)d_in[6];
  const float* bnb   = (const float*)d_in[7];
  const float* Wself = (const float*)d_in[8];
  const float* bself = (const float*)d_in[9];
  const float* Watt  = (const float*)d_in[10];
  const float* batt  = (const float*)d_in[11];
  float* wsf = (float*)d_ws;

  // workspace layout (4-byte units), ~4.31M (~17.2 MB)
  float* y      = wsf + 0;                     // N*12
  float* hw     = wsf + 1200000;               // N*8
  int*   ssrc   = (int*)(wsf + 2000000);       // E
  int*   cnt    = (int*)(wsf + 3600000);       // N
  int*   off    = (int*)(wsf + 3700000);       // N+1
  int*   cursor = (int*)(wsf + 3800064);       // N
  float* dinv1  = wsf + 3900064;               // N
  float* dinv2  = wsf + 4000064;               // N
  float* s1c    = wsf + 4100064;               // N
  float* s2c    = wsf + 4200064;               // N
  int*   bsum   = (int*)(wsf + 4300064);       // 391
  int*   bpre   = (int*)(wsf + 4300512);       // 391
  float* w0m    = wsf + 4301056;               // 512*12
  float* kc     = wsf + 4307200;               // 12

  float* out = (float*)d_out;

  k_zero_cnt<<<SCAN_NB, 256, 0, stream>>>(cnt, N_NODES);
  k_prep<<<1, 256, 0, stream>>>(W0, b0, W1, Wnb, bnb, Wself, bself, Watt, batt, w0m, kc);
  k_count4<<<(N_EDGES / 4 + 255) / 256, 256, 0, stream>>>(col, cnt);
  k_gemm_y<<<6250, 256, 0, stream>>>(x, w0m, y);
  k_scan1<<<SCAN_NB, 256, 0, stream>>>(cnt, off, bsum);
  k_scan2<<<1, 512, 0, stream>>>(bsum, bpre);
  k_scan3<<<SCAN_NB, 256, 0, stream>>>(cnt, bpre, off, cursor, dinv1);
  {
    int chunks = (N_EDGES / 4 + 255) / 256;  // 1563
    k_scatter<<<chunks * 8, 256, 0, stream>>>(row, col, cursor, ssrc);
  }
  k_agg1<<<(N_NODES * 4 + 255) / 256, 256, 0, stream>>>(off, ssrc, y, dinv1, kc, hw, s1c, s2c);
  k_deg2g<<<SCAN_NB, 256, 0, stream>>>(off, ssrc, s1c, s2c, dinv2);
  k_conv2g<<<(N_NODES * 2 + 255) / 256, 256, 0, stream>>>(off, ssrc, hw, s1c, s2c, dinv2, b1, out);
}

// Round 4
// 588.838 us; speedup vs baseline: 1.0628x; 1.0628x over previous
//
#include <hip/hip_runtime.h>
#include <cstdint>

#define N_NODES 100000
#define N_EDGES 1600000
#define SCAN_NB 391   // ceil(N_NODES/256)
#define YD 12         // padded projected dim: [hw0..7, p1, p2, pad, pad]
#define SC_RANGE 12500

// ---------------- prep: M = [W1 | u1 | u2], w0m_t = (W0 @ M)^T  [10][512], kc ----------------
__global__ __launch_bounds__(256) void k_prep(
    const float* __restrict__ W0, const float* __restrict__ b0,
    const float* __restrict__ W1,
    const float* __restrict__ Wnb, const float* __restrict__ bnb,
    const float* __restrict__ Wself, const float* __restrict__ bself,
    const float* __restrict__ Watt, const float* __restrict__ batt,
    float* __restrict__ w0m_t, float* __restrict__ kc) {
  __shared__ float M[32][10];
  int t = threadIdx.x;
  if (t < 32) {
    for (int j = 0; j < 8; ++j) M[t][j] = W1[t * 8 + j];
    float a1 = 0.f, a2 = 0.f;
    for (int j = 0; j < 8; ++j) {
      a1 += Wnb[t * 8 + j] * Watt[j];
      a2 += Wself[t * 8 + j] * Watt[8 + j];
    }
    M[t][8] = a1; M[t][9] = a2;
  }
  __syncthreads();
  // w0m_t[j][k] = sum_m W0[k][m] * M[m][j]
  for (int o = t; o < 10 * 512; o += 256) {
    int j = o >> 9, k = o & 511;
    float a = 0.f;
    for (int m = 0; m < 32; ++m) a += W0[k * 32 + m] * M[m][j];
    w0m_t[o] = a;
  }
  if (t < 10) {
    float a = 0.f;
    for (int m = 0; m < 32; ++m) a += b0[m] * M[m][t];
    if (t == 8) { for (int j = 0; j < 8; ++j) a += bnb[j] * Watt[j]; a += batt[0]; }
    if (t == 9) { for (int j = 0; j < 8; ++j) a += bself[j] * Watt[8 + j]; }
    kc[t] = a;
  }
  if (t >= 10 && t < 12) kc[t] = 0.f;
}

// ---------------- y = x @ w0m  : 8 rows per wave, 3-stage reduce ----------------
// 3125 blocks x 4 waves x 8 rows = 100000 exactly.
__global__ __launch_bounds__(256) void k_gemm_y(const float* __restrict__ x,
                                                const float* __restrict__ w0m_t,
                                                float* __restrict__ y) {
  __shared__ float wl[10 * 512];  // 20 KB, transposed [j][k]
  {
    const float4* src = (const float4*)w0m_t;
    float4* dst = (float4*)wl;
    for (int f = threadIdx.x; f < 1280; f += 256) dst[f] = src[f];
  }
  __syncthreads();
  const int lane = threadIdx.x & 63;
  const int wave = (blockIdx.x << 2) + (threadIdx.x >> 6);
  const int p = lane & 7;          // k-slice within row
  const int rsub = lane >> 3;      // row within wave
  const int row = wave * 8 + rsub;
  const float* xr = x + (size_t)row * 512;
  float acc[10];
#pragma unroll
  for (int j = 0; j < 10; ++j) acc[j] = 0.f;
#pragma unroll 4
  for (int it = 0; it < 16; ++it) {
    const int k0 = it * 32 + p * 4;
    float4 xv = *(const float4*)(xr + k0);
#pragma unroll
    for (int j = 0; j < 10; ++j) {
      float4 wv = *(const float4*)&wl[j * 512 + k0];
      acc[j] += xv.x * wv.x + xv.y * wv.y + xv.z * wv.z + xv.w * wv.w;
    }
  }
  // reduce over the 8-lane k-group (same row)
#pragma unroll
  for (int d = 1; d < 8; d <<= 1)
#pragma unroll
    for (int j = 0; j < 10; ++j) acc[j] += __shfl_xor(acc[j], d, 64);
  float* yp = y + (size_t)row * YD;
  if (p == 0) {
    *(float4*)yp       = make_float4(acc[0], acc[1], acc[2], acc[3]);
    *(float4*)(yp + 4) = make_float4(acc[4], acc[5], acc[6], acc[7]);
  } else if (p == 1) {
    *(float2*)(yp + 8) = make_float2(acc[8], acc[9]);
  }
}

// ---------------- CSR build ----------------
__global__ void k_zero_cnt(int* __restrict__ cnt, int n) {
  int i = blockIdx.x * 256 + threadIdx.x;
  if (i < n) cnt[i] = 0;
}

__global__ void k_count4(const int* __restrict__ col, int* __restrict__ cnt) {
  int e0 = (blockIdx.x * 256 + threadIdx.x) * 4;
  if (e0 >= N_EDGES) return;
  int4 c = *(const int4*)(col + e0);
  atomicAdd(&cnt[c.x], 1); atomicAdd(&cnt[c.y], 1);
  atomicAdd(&cnt[c.z], 1); atomicAdd(&cnt[c.w], 1);
}

__global__ __launch_bounds__(256) void k_scan1(const int* __restrict__ cnt,
                                               int* __restrict__ off,
                                               int* __restrict__ bsum) {
  __shared__ int s[256];
  int t = threadIdx.x;
  int i = blockIdx.x * 256 + t;
  int v = (i < N_NODES) ? cnt[i] : 0;
  s[t] = v;
  __syncthreads();
  for (int d = 1; d < 256; d <<= 1) {
    int a = (t >= d) ? s[t - d] : 0;
    __syncthreads();
    s[t] += a;
    __syncthreads();
  }
  if (i < N_NODES) off[i] = s[t] - v;
  if (t == 255) bsum[blockIdx.x] = s[255];
}

__global__ __launch_bounds__(512) void k_scan2(const int* __restrict__ bsum,
                                               int* __restrict__ bpre) {
  __shared__ int s[512];
  int t = threadIdx.x;
  int v = (t < SCAN_NB) ? bsum[t] : 0;
  s[t] = v;
  __syncthreads();
  for (int d = 1; d < 512; d <<= 1) {
    int a = (t >= d) ? s[t - d] : 0;
    __syncthreads();
    s[t] += a;
    __syncthreads();
  }
  if (t < SCAN_NB) bpre[t] = s[t] - v;
}

__global__ void k_scan3(const int* __restrict__ cnt, const int* __restrict__ bpre,
                        int* __restrict__ off, int* __restrict__ cursor,
                        float* __restrict__ dinv1) {
  int i = blockIdx.x * 256 + threadIdx.x;
  if (i >= N_NODES) return;
  int o = off[i] + bpre[i >> 8];
  off[i] = o;
  cursor[i] = o;
  dinv1[i] = rsqrtf((float)cnt[i] + 1.0f);
  if (i == 0) off[N_NODES] = N_EDGES;
}

// XCD-localized scatter: range = blockIdx & 7
__global__ void k_scatter(const int* __restrict__ row, const int* __restrict__ col,
                          int* __restrict__ cursor, int* __restrict__ ssrc) {
  int range = blockIdx.x & 7;
  int chunk = blockIdx.x >> 3;
  int e0 = (chunk * 256 + threadIdx.x) * 4;
  if (e0 >= N_EDGES) return;
  int lo = range * SC_RANGE, hi = lo + SC_RANGE;
  int4 c4 = *(const int4*)(col + e0);
  int4 r4 = *(const int4*)(row + e0);
  int cs[4] = {c4.x, c4.y, c4.z, c4.w};
  int rs[4] = {r4.x, r4.y, r4.z, r4.w};
#pragma unroll
  for (int k = 0; k < 4; ++k) {
    int c = cs[k];
    if (c >= lo && c < hi) {
      int p = atomicAdd(&cursor[c], 1);
      ssrc[p] = rs[k];
    }
  }
}

// ---------------- conv1 aggregation on projected 10-dim y ----------------
__global__ void k_agg1(const int* __restrict__ off, const int* __restrict__ ssrc,
                       const float* __restrict__ y, const float* __restrict__ dinv1,
                       const float* __restrict__ kc, float* __restrict__ hw,
                       float* __restrict__ s1c, float* __restrict__ s2c) {
  int tid = blockIdx.x * 256 + threadIdx.x;  // N*4
  if (tid >= N_NODES * 4) return;
  int i = tid >> 2, q = tid & 3;
  if (q == 3) return;
  int p0 = off[i], p1 = off[i + 1];
  float di = dinv1[i];
  float d2 = di * di;
  if (q < 2) {
    float4 acc = make_float4(0.f, 0.f, 0.f, 0.f);
    for (int p = p0; p < p1; ++p) {
      int r = ssrc[p];
      float dr = dinv1[r];
      float4 v = *(const float4*)(y + (size_t)r * YD + q * 4);
      acc.x += v.x * dr; acc.y += v.y * dr; acc.z += v.z * dr; acc.w += v.w * dr;
    }
    float4 sv = *(const float4*)(y + (size_t)i * YD + q * 4);
    float4 kq = *(const float4*)(kc + q * 4);
    *(float4*)(hw + (size_t)i * 8 + q * 4) =
        make_float4(di * acc.x + d2 * sv.x + kq.x, di * acc.y + d2 * sv.y + kq.y,
                    di * acc.z + d2 * sv.z + kq.z, di * acc.w + d2 * sv.w + kq.w);
  } else {
    float a8 = 0.f, a9 = 0.f;
    for (int p = p0; p < p1; ++p) {
      int r = ssrc[p];
      float dr = dinv1[r];
      float4 v = *(const float4*)(y + (size_t)r * YD + 8);
      a8 += v.x * dr; a9 += v.y * dr;
    }
    float4 sv = *(const float4*)(y + (size_t)i * YD + 8);
    s1c[i] = di * a8 + d2 * sv.x + kc[8];
    s2c[i] = di * a9 + d2 * sv.y + kc[9];
  }
}

// ---------------- deg2 gather (gate on the fly) ----------------
__global__ void k_deg2g(const int* __restrict__ off, const int* __restrict__ ssrc,
                        const float* __restrict__ s1c, const float* __restrict__ s2c,
                        float* __restrict__ dinv2) {
  int i = blockIdx.x * 256 + threadIdx.x;
  if (i >= N_NODES) return;
  float s2i = s2c[i];
  float sum = 0.f;
  int p1 = off[i + 1];
  for (int p = off[i]; p < p1; ++p) {
    int r = ssrc[p];
    float w = fmaxf(s1c[r] + s2i, 0.f);
    float m = fminf(1.01f / (1.f + __expf(-w)), 1.f);
    sum += m * w;
  }
  dinv2[i] = rsqrtf(sum + 1.0f);
}

// ---------------- conv2 gather, self-loop + bias fused ----------------
__global__ void k_conv2g(const int* __restrict__ off, const int* __restrict__ ssrc,
                         const float* __restrict__ hw, const float* __restrict__ s1c,
                         const float* __restrict__ s2c, const float* __restrict__ dinv2,
                         const float* __restrict__ b1, float* __restrict__ out) {
  int tid = blockIdx.x * 256 + threadIdx.x;  // N*2
  if (tid >= N_NODES * 2) return;
  int i = tid >> 1, q = tid & 1;
  float s2i = s2c[i];
  float di = dinv2[i];
  float4 acc = make_float4(0.f, 0.f, 0.f, 0.f);
  int p1 = off[i + 1];
  for (int p = off[i]; p < p1; ++p) {
    int r = ssrc[p];
    float w = fmaxf(s1c[r] + s2i, 0.f);
    float m = fminf(1.01f / (1.f + __expf(-w)), 1.f);
    float cf = m * w * dinv2[r];
    float4 v = *(const float4*)(hw + (size_t)r * 8 + q * 4);
    acc.x += v.x * cf; acc.y += v.y * cf; acc.z += v.z * cf; acc.w += v.w * cf;
  }
  float4 sv = *(const float4*)(hw + (size_t)i * 8 + q * 4);
  float4 bq = *(const float4*)(b1 + q * 4);
  float d2 = di * di;
  *(float4*)(out + (size_t)i * 8 + q * 4) =
      make_float4(di * acc.x + d2 * sv.x + bq.x, di * acc.y + d2 * sv.y + bq.y,
                  di * acc.z + d2 * sv.z + bq.z, di * acc.w + d2 * sv.w + bq.w);
}

extern "C" void kernel_launch(void* const* d_in, const int* in_sizes, int n_in,
                              void* d_out, int out_size, void* d_ws, size_t ws_size,
                              hipStream_t stream) {
  const float* x     = (const float*)d_in[0];
  const int*   eidx  = (const int*)d_in[1];
  const int*   row   = eidx;
  const int*   col   = eidx + N_EDGES;
  const float* W0    = (const float*)d_in[2];
  const float* b0    = (const float*)d_in[3];
  const float* W1    = (const float*)d_in[4];
  const float* b1    = (const float*)d_in[5];
  const float* Wnb   = (const float*)d_in[6];
  const float* bnb   = (const float*)d_in[7];
  const float* Wself = (const float*)d_in[8];
  const float* bself = (const float*)d_in[9];
  const float* Watt  = (const float*)d_in[10];
  const float* batt  = (const float*)d_in[11];
  float* wsf = (float*)d_ws;

  // workspace layout (4-byte units), ~4.31M (~17.2 MB)
  float* y      = wsf + 0;                     // N*12
  float* hw     = wsf + 1200000;               // N*8
  int*   ssrc   = (int*)(wsf + 2000000);       // E
  int*   cnt    = (int*)(wsf + 3600000);       // N
  int*   off    = (int*)(wsf + 3700000);       // N+1
  int*   cursor = (int*)(wsf + 3800064);       // N
  float* dinv1  = wsf + 3900064;               // N
  float* dinv2  = wsf + 4000064;               // N
  float* s1c    = wsf + 4100064;               // N
  float* s2c    = wsf + 4200064;               // N
  int*   bsum   = (int*)(wsf + 4300064);       // 391
  int*   bpre   = (int*)(wsf + 4300512);       // 391
  float* w0m_t  = wsf + 4301056;               // 10*512
  float* kc     = wsf + 4306176;               // 12

  float* out = (float*)d_out;

  k_zero_cnt<<<SCAN_NB, 256, 0, stream>>>(cnt, N_NODES);
  k_prep<<<1, 256, 0, stream>>>(W0, b0, W1, Wnb, bnb, Wself, bself, Watt, batt, w0m_t, kc);
  k_count4<<<(N_EDGES / 4 + 255) / 256, 256, 0, stream>>>(col, cnt);
  k_gemm_y<<<3125, 256, 0, stream>>>(x, w0m_t, y);
  k_scan1<<<SCAN_NB, 256, 0, stream>>>(cnt, off, bsum);
  k_scan2<<<1, 512, 0, stream>>>(bsum, bpre);
  k_scan3<<<SCAN_NB, 256, 0, stream>>>(cnt, bpre, off, cursor, dinv1);
  {
    int chunks = (N_EDGES / 4 + 255) / 256;  // 1563
    k_scatter<<<chunks * 8, 256, 0, stream>>>(row, col, cursor, ssrc);
  }
  k_agg1<<<(N_NODES * 4 + 255) / 256, 256, 0, stream>>>(off, ssrc, y, dinv1, kc, hw, s1c, s2c);
  k_deg2g<<<SCAN_NB, 256, 0, stream>>>(off, ssrc, s1c, s2c, dinv2);
  k_conv2g<<<(N_NODES * 2 + 255) / 256, 256, 0, stream>>>(off, ssrc, hw, s1c, s2c, dinv2, b1, out);
}